// Round 9
// baseline (176.464 us; speedup 1.0000x reference)
//
#include <hip/hip_runtime.h>
#include <hip/hip_fp16.h>
#include <math.h>

#define NB   16     // batch
#define IMG  128    // input image side
#define NANG 300
#define NDET 300
#define WB   148    // canvas live box: x,y in [76,224)

typedef _Float16 v2h __attribute__((ext_vector_type(2)));

// Gaussian taps: sigma_img -> 2^(-d^2/2); sigma_att -> 2^(-d^2/8). f64 normalize, f32 cast.
__device__ __constant__ float KE[9] = {
  (float)(0.00390625            / 3.0104144100214136),
  (float)(0.04419417382415922   / 3.0104144100214136),
  (float)(0.25                  / 3.0104144100214136),
  (float)(0.7071067811865476    / 3.0104144100214136),
  (float)(1.0                   / 3.0104144100214136),
  (float)(0.7071067811865476    / 3.0104144100214136),
  (float)(0.25                  / 3.0104144100214136),
  (float)(0.04419417382415922   / 3.0104144100214136),
  (float)(0.00390625            / 3.0104144100214136)
};
__device__ __constant__ float KA[17] = {
  (float)(0.00390625            / 6.019333926786741),
  (float)(0.014328188175072987  / 6.019333926786741),
  (float)(0.04419417382415922   / 6.019333926786741),
  (float)(0.11462550540058389   / 6.019333926786741),
  (float)(0.25                  / 6.019333926786741),
  (float)(0.4585020216023356    / 6.019333926786741),
  (float)(0.7071067811865476    / 6.019333926786741),
  (float)(0.9170040432046712    / 6.019333926786741),
  (float)(1.0                   / 6.019333926786741),
  (float)(0.9170040432046712    / 6.019333926786741),
  (float)(0.7071067811865476    / 6.019333926786741),
  (float)(0.4585020216023356    / 6.019333926786741),
  (float)(0.25                  / 6.019333926786741),
  (float)(0.11462550540058389   / 6.019333926786741),
  (float)(0.04419417382415922   / 6.019333926786741),
  (float)(0.014328188175072987  / 6.019333926786741),
  (float)(0.00390625            / 6.019333926786741)
};

__device__ __forceinline__ unsigned h16(float f) {
  return (unsigned)__half_as_ushort(__float2half_rn(f));
}
__device__ __forceinline__ v2h pk16(float a, float b) {
  return __builtin_bit_cast(v2h, __builtin_amdgcn_cvt_pkrtz(a, b));
}

// K1: fused pad+blur -> two half-batch f16 quad canvases over the live box [76,224)^2.
// Q[h][y'][x'][bb] = uint4{ E00|E01<<16, E10|E11<<16, A00|A01<<16, A10|A11<<16 }
// (f16 pairs; suffix (r,c) = (y+r, x+c); A pre-scaled 0.01; h = b>>3, bb = b&7).
// Each half canvas is 148*148*8*16 B = 2.80 MB -> fits one XCD's 4 MiB L2.
__global__ void k_prep(const float* __restrict__ img, const float* __restrict__ att,
                       uint4* __restrict__ Q) {
  __shared__ float sImg[25 * 25];   // img rows Y0-14 .. Y0+10, cols X0-14 .. X0+10
  __shared__ float sAtt[33 * 33];   // att rows Y0-18 .. Y0+14, cols X0-18 .. X0+14
  __shared__ float sEi[25 * 17];    // h-blurred E rows, canvas cols X0 .. X0+16
  __shared__ float sAi[33 * 17];

  int tid = threadIdx.x;
  int tx = tid & 15, ty = tid >> 4;
  int X0 = blockIdx.x * 16;         // canvas-box coords
  int Y0 = blockIdx.y * 16;
  int b  = blockIdx.z;
  const float* imb = img + b * IMG * IMG;
  const float* atb = att + b * IMG * IMG;
  for (int t = tid; t < 625; t += 256) {
    int r = t / 25, c = t - r * 25;
    int ir = Y0 - 14 + r, ic = X0 - 14 + c;
    bool v = (ir >= 0) & (ir < IMG) & (ic >= 0) & (ic < IMG);
    sImg[t] = v ? imb[ir * IMG + ic] : 0.f;
  }
  for (int t = tid; t < 1089; t += 256) {
    int r = t / 33, c = t - r * 33;
    int ir = Y0 - 18 + r, ic = X0 - 18 + c;
    bool v = (ir >= 0) & (ir < IMG) & (ic >= 0) & (ic < IMG);
    sAtt[t] = v ? atb[ir * IMG + ic] : 0.f;
  }
  __syncthreads();
  for (int t = tid; t < 425; t += 256) {   // 25*17
    int r = t / 17, c = t - r * 17;
    float acc = 0.f;
#pragma unroll
    for (int d = 0; d < 9; ++d) acc = fmaf(KE[d], sImg[r * 25 + c + d], acc);
    sEi[t] = acc;
  }
  for (int t = tid; t < 561; t += 256) {   // 33*17
    int r = t / 17, c = t - r * 17;
    float acc = 0.f;
#pragma unroll
    for (int d = 0; d < 17; ++d) acc = fmaf(KA[d], sAtt[r * 33 + c + d], acc);
    sAi[t] = acc;
  }
  __syncthreads();
  int xc = X0 + tx, yc = Y0 + ty;
  if (xc >= WB || yc >= WB) return;
  float E00 = 0.f, E01 = 0.f, E10 = 0.f, E11 = 0.f;
  float A00 = 0.f, A01 = 0.f, A10 = 0.f, A11 = 0.f;
#pragma unroll
  for (int d = 0; d < 9; ++d) {
    float k = KE[d];
    E00 = fmaf(k, sEi[(ty + d) * 17 + tx],     E00);
    E01 = fmaf(k, sEi[(ty + d) * 17 + tx + 1], E01);
    E10 = fmaf(k, sEi[(ty + 1 + d) * 17 + tx],     E10);
    E11 = fmaf(k, sEi[(ty + 1 + d) * 17 + tx + 1], E11);
  }
#pragma unroll
  for (int d = 0; d < 17; ++d) {
    float k = KA[d];
    A00 = fmaf(k, sAi[(ty + d) * 17 + tx],     A00);
    A01 = fmaf(k, sAi[(ty + d) * 17 + tx + 1], A01);
    A10 = fmaf(k, sAi[(ty + 1 + d) * 17 + tx],     A10);
    A11 = fmaf(k, sAi[(ty + 1 + d) * 17 + tx + 1], A11);
  }
  uint4 q;
  q.x = h16(E00) | (h16(E01) << 16);
  q.y = h16(E10) | (h16(E11) << 16);
  q.z = h16(0.01f * A00) | (h16(0.01f * A01) << 16);
  q.w = h16(0.01f * A10) | (h16(0.01f * A11) << 16);
  Q[((b >> 3) * WB * WB + yc * WB + xc) * 8 + (b & 7)] = q;
}

// K2: radon for E and A together over half-batch canvases.
// blockIdx.x in [0,20): half = x&1 (parity -> alternating XCDs under round-robin
// dispatch, so each XCD's L2 caches only its 2.8 MB half), jblock = x>>1.
// Lanes: bb = t&7 (8 lanes consume one 128-B pixel line), 8 bins/wave.
// ONE dwordx4 per sample; bilinear = 1 pkrtz + 4 fdot2 + 4 fma.
// Tail samples clamped to chord end 'hi' -> guaranteed-zero canvas -> exact 0.
__global__ void k_radon(const uint4* __restrict__ P, float* __restrict__ S) {
  int t = threadIdx.x;
  int bb = t & 7;
  int jj = t >> 3;                   // [0,32)
  int xb = blockIdx.x;
  int half = xb & 1;
  int j  = (xb >> 1) * 32 + jj;
  int a  = blockIdx.y;
  if (j >= NDET) return;
  float th = (float)a * (float)(3.14159265358979323846 / 299.0);
  float c = cosf(th), s = sinf(th);
  float xj = fmaf((float)j, (float)(2.0 / 299.0), -1.0f);
  // px(i) = pb + s*i ; py(i) = qb + c*i (unit step)
  float pb = fmaf(c,  xj, 1.0f) * 149.5f - 149.5f * s;
  float qb = fmaf(-s, xj, 1.0f) * 149.5f - 149.5f * c;
  const float L = 76.5f, H = 222.5f;
  float lo = 0.f, hi = 299.0f;
  if (s > 1e-6f) {                   // s >= 0 for theta in [0,180]
    float inv = 1.0f / s;
    lo = fmaxf(lo, (L - pb) * inv); hi = fminf(hi, (H - pb) * inv);
  } else if (pb < L || pb > H) { hi = -1.f; }
  if (fabsf(c) > 1e-6f) {
    float inv = 1.0f / c;
    float t0 = (L - qb) * inv, t1 = (H - qb) * inv;
    lo = fmaxf(lo, fminf(t0, t1)); hi = fminf(hi, fmaxf(t0, t1));
  } else if (qb < L || qb > H) { hi = -1.f; }
  int i0 = (int)ceilf(lo);
  int i1 = (int)floorf(hi);

  float sE0 = 0.f, sE1 = 0.f, sA0 = 0.f, sA1 = 0.f;
  // byte offset for (y0,x0): ((y0-76)*148 + (x0-76))*128 + bb*16
  const char* Pc = (const char*)P + half * (WB * WB * 128);
  int boff = bb * 16 - 76 * 149 * 128;

  for (int i = i0; i <= i1; i += 8) {
    uint4 q[8];
    v2h oxp[8];
    float wyv[8];
#pragma unroll
    for (int u = 0; u < 8; ++u) {
      float fi = fminf((float)(i + u), hi);   // tail -> chord end -> zero canvas
      float px = fmaf(fi, s, pb);
      float py = fmaf(fi, c, qb);
      float x0f = floorf(px), y0f = floorf(py);
      float wx = px - x0f;
      wyv[u] = py - y0f;
      int idx = (int)fmaf(y0f, (float)WB, x0f);
      int off = (idx << 7) + boff;
      q[u] = *(const uint4*)(Pc + off);
      oxp[u] = pk16(1.0f - wx, wx);
    }
#pragma unroll
    for (int u = 0; u < 8; ++u) {
      float wy = wyv[u], omy = 1.0f - wy;
      float de0 = __builtin_amdgcn_fdot2(__builtin_bit_cast(v2h, q[u].x), oxp[u], 0.0f, false);
      float de1 = __builtin_amdgcn_fdot2(__builtin_bit_cast(v2h, q[u].y), oxp[u], 0.0f, false);
      float da0 = __builtin_amdgcn_fdot2(__builtin_bit_cast(v2h, q[u].z), oxp[u], 0.0f, false);
      float da1 = __builtin_amdgcn_fdot2(__builtin_bit_cast(v2h, q[u].w), oxp[u], 0.0f, false);
      if (u & 1) { sE1 = fmaf(omy, de0, fmaf(wy, de1, sE1)); sA1 = fmaf(omy, da0, fmaf(wy, da1, sA1)); }
      else       { sE0 = fmaf(omy, de0, fmaf(wy, de1, sE0)); sA0 = fmaf(omy, da0, fmaf(wy, da1, sA0)); }
    }
  }
  float sumE = sE0 + sE1, sumA = sA0 + sA1;
  int b = half * 8 + bb;
  S[(a * NB + b) * NDET + j] = sumE * expf(-2.0f * sumA);  // VOXEL_MM = 2; layout [a][b][j]
}

// K3: per-angle 5-tap detector blur (reflect) + scale. S is [a][b][j] -> fully
// coalesced reads along j; out [b][a][j] coalesced writes.
__global__ void k_dblur(const float* __restrict__ S, const float* __restrict__ scale,
                        float* __restrict__ out) {
  int j = threadIdx.x;
  int a = blockIdx.x;
  int b = blockIdx.y;
  if (j >= NDET) return;
  float th = (float)a * (float)(3.14159265358979323846 / 299.0);
  float c = cosf(th), s = sinf(th);
  float u = fabsf(c) + fabsf(s);          // bw = 2u
  float u2 = u * u;
  float e1 = exp2f(-2.0f * u2);
  float e2 = exp2f(-8.0f * u2);
  float norm = 1.0f / (1.0f + 2.0f * (e1 + e2));
  float w2c = norm, w1c = e1 * norm, w0c = e2 * norm;
  const float* row = S + (a * NB + b) * NDET;
  float acc = 0.f;
#pragma unroll
  for (int tt = -2; tt <= 2; ++tt) {
    int jr = j + tt;
    if (jr < 0) jr = -jr;
    if (jr > 299) jr = 598 - jr;
    float w = (tt == 0) ? w2c : ((tt == 1 || tt == -1) ? w1c : w0c);
    acc = fmaf(w, row[jr], acc);
  }
  out[(b * NANG + a) * NDET + j] = acc * scale[b];
}

extern "C" void kernel_launch(void* const* d_in, const int* in_sizes, int n_in,
                              void* d_out, int out_size, void* d_ws, size_t ws_size,
                              hipStream_t stream) {
  const float* img   = (const float*)d_in[0];
  const float* att   = (const float*)d_in[1];
  const float* scale = (const float*)d_in[2];
  float* out = (float*)d_out;
  float* ws  = (float*)d_ws;

  // ws layout (floats): Q 2*148*148*8 uint4 (5.61 MB) | S 300*300*16 (5.76 MB)
  uint4*  Q  = (uint4*)ws;
  float*  S  = ws + 1401856;

  k_prep <<<dim3(10, 10, NB), 256, 0, stream>>>(img, att, Q);
  k_radon<<<dim3(20, NANG),   256, 0, stream>>>(Q, S);
  k_dblur<<<dim3(NANG, NB),   320, 0, stream>>>(S, scale, out);
}

// Round 12
// 156.138 us; speedup vs baseline: 1.1302x; 1.1302x over previous
//
#include <hip/hip_runtime.h>
#include <hip/hip_fp16.h>
#include <math.h>

#define NB   16     // batch
#define IMG  128    // input image side
#define NANG 300
#define NDET 300
#define WB   148    // canvas live box: x,y in [76,224)

typedef _Float16 v2h __attribute__((ext_vector_type(2)));

// Gaussian taps: sigma_img -> 2^(-d^2/2); sigma_att -> 2^(-d^2/8). f64 normalize, f32 cast.
__device__ __constant__ float KE[9] = {
  (float)(0.00390625            / 3.0104144100214136),
  (float)(0.04419417382415922   / 3.0104144100214136),
  (float)(0.25                  / 3.0104144100214136),
  (float)(0.7071067811865476    / 3.0104144100214136),
  (float)(1.0                   / 3.0104144100214136),
  (float)(0.7071067811865476    / 3.0104144100214136),
  (float)(0.25                  / 3.0104144100214136),
  (float)(0.04419417382415922   / 3.0104144100214136),
  (float)(0.00390625            / 3.0104144100214136)
};
__device__ __constant__ float KA[17] = {
  (float)(0.00390625            / 6.019333926786741),
  (float)(0.014328188175072987  / 6.019333926786741),
  (float)(0.04419417382415922   / 6.019333926786741),
  (float)(0.11462550540058389   / 6.019333926786741),
  (float)(0.25                  / 6.019333926786741),
  (float)(0.4585020216023356    / 6.019333926786741),
  (float)(0.7071067811865476    / 6.019333926786741),
  (float)(0.9170040432046712    / 6.019333926786741),
  (float)(1.0                   / 6.019333926786741),
  (float)(0.9170040432046712    / 6.019333926786741),
  (float)(0.7071067811865476    / 6.019333926786741),
  (float)(0.4585020216023356    / 6.019333926786741),
  (float)(0.25                  / 6.019333926786741),
  (float)(0.11462550540058389   / 6.019333926786741),
  (float)(0.04419417382415922   / 6.019333926786741),
  (float)(0.014328188175072987  / 6.019333926786741),
  (float)(0.00390625            / 6.019333926786741)
};

__device__ __forceinline__ unsigned h16(float f) {
  return (unsigned)__half_as_ushort(__float2half_rn(f));
}
__device__ __forceinline__ unsigned pk16u(float a, float b) {
  return __builtin_bit_cast(unsigned, __builtin_amdgcn_cvt_pkrtz(a, b));
}
__device__ __forceinline__ float fdot2(unsigned q, unsigned w, float acc) {
  return __builtin_amdgcn_fdot2(__builtin_bit_cast(v2h, q), __builtin_bit_cast(v2h, w), acc, false);
}

// K1: fused pad+blur -> f16 quad canvas over the live box [76,224)^2.
// Q[y'][x'][b] = uint4{ E00|E01<<16, E10|E11<<16, A00|A01<<16, A10|A11<<16 }
// (f16 pairs; suffix (r,c) = (y+r, x+c); A pre-scaled 0.01). Whole 2x2 bilinear
// footprint of both images in ONE 16-B load for k_radon.
__global__ void k_prep(const float* __restrict__ img, const float* __restrict__ att,
                       uint4* __restrict__ Q) {
  __shared__ float sImg[25 * 25];
  __shared__ float sAtt[33 * 33];
  __shared__ float sEi[25 * 17];
  __shared__ float sAi[33 * 17];

  int tid = threadIdx.x;
  int tx = tid & 15, ty = tid >> 4;
  int X0 = blockIdx.x * 16;
  int Y0 = blockIdx.y * 16;
  int b  = blockIdx.z;
  const float* imb = img + b * IMG * IMG;
  const float* atb = att + b * IMG * IMG;
  for (int t = tid; t < 625; t += 256) {
    int r = t / 25, c = t - r * 25;
    int ir = Y0 - 14 + r, ic = X0 - 14 + c;
    bool v = (ir >= 0) & (ir < IMG) & (ic >= 0) & (ic < IMG);
    sImg[t] = v ? imb[ir * IMG + ic] : 0.f;
  }
  for (int t = tid; t < 1089; t += 256) {
    int r = t / 33, c = t - r * 33;
    int ir = Y0 - 18 + r, ic = X0 - 18 + c;
    bool v = (ir >= 0) & (ir < IMG) & (ic >= 0) & (ic < IMG);
    sAtt[t] = v ? atb[ir * IMG + ic] : 0.f;
  }
  __syncthreads();
  for (int t = tid; t < 425; t += 256) {
    int r = t / 17, c = t - r * 17;
    float acc = 0.f;
#pragma unroll
    for (int d = 0; d < 9; ++d) acc = fmaf(KE[d], sImg[r * 25 + c + d], acc);
    sEi[t] = acc;
  }
  for (int t = tid; t < 561; t += 256) {
    int r = t / 17, c = t - r * 17;
    float acc = 0.f;
#pragma unroll
    for (int d = 0; d < 17; ++d) acc = fmaf(KA[d], sAtt[r * 33 + c + d], acc);
    sAi[t] = acc;
  }
  __syncthreads();
  int xc = X0 + tx, yc = Y0 + ty;
  if (xc >= WB || yc >= WB) return;
  float E00 = 0.f, E01 = 0.f, E10 = 0.f, E11 = 0.f;
  float A00 = 0.f, A01 = 0.f, A10 = 0.f, A11 = 0.f;
#pragma unroll
  for (int d = 0; d < 9; ++d) {
    float k = KE[d];
    E00 = fmaf(k, sEi[(ty + d) * 17 + tx],     E00);
    E01 = fmaf(k, sEi[(ty + d) * 17 + tx + 1], E01);
    E10 = fmaf(k, sEi[(ty + 1 + d) * 17 + tx],     E10);
    E11 = fmaf(k, sEi[(ty + 1 + d) * 17 + tx + 1], E11);
  }
#pragma unroll
  for (int d = 0; d < 17; ++d) {
    float k = KA[d];
    A00 = fmaf(k, sAi[(ty + d) * 17 + tx],     A00);
    A01 = fmaf(k, sAi[(ty + d) * 17 + tx + 1], A01);
    A10 = fmaf(k, sAi[(ty + 1 + d) * 17 + tx],     A10);
    A11 = fmaf(k, sAi[(ty + 1 + d) * 17 + tx + 1], A11);
  }
  uint4 q;
  q.x = h16(E00) | (h16(E01) << 16);
  q.y = h16(E10) | (h16(E11) << 16);
  q.z = h16(0.01f * A00) | (h16(0.01f * A01) << 16);
  q.w = h16(0.01f * A10) | (h16(0.01f * A11) << 16);
  Q[(yc * WB + xc) * NB + b] = q;
}

// K2: radon with wave-local LDS coordinate pipeline.
// Block 256 = 16 j x 16 b; wave = 4 j x 16 b. Per 16-sample chunk:
//   Phase A: each lane computes coords+weights for a DISTINCT (j, i) (its b-slot
//            acts as i-offset) -> {pixel_off, w0, w1} to per-wave LDS region
//            (LDS is wave-ordered; wave_barrier() = compiler scheduling fence).
//   Phase B: 16 u-steps: broadcast ds_read_b128 + addr add + dwordx4 + 4 fdot2.
// Coordinate clamp px,py -> [76.5, 222.0] BEFORE floor:
//   * identity for in-chord samples (exact);
//   * any out-of-chord/degenerate sample lands on cols/rows {76,77} or {222,223},
//     which are all-zero for E (support [82,218)) and A (support [78,222)) -> its
//     weighted contribution is exactly 0; all addresses in-bounds by construction.
__global__ void __launch_bounds__(256)
k_radon(const uint4* __restrict__ P, float* __restrict__ S) {
  __shared__ uint4 sLds[16 * 17];       // row jrow*17 + u ; 17-stride kills bank conflicts

  int t = threadIdx.x;
  int b    = t & 15;                    // phase B: batch lane ; phase A: i-offset
  int jrow = t >> 4;                    // 0..15
  int j  = blockIdx.x * 16 + jrow;
  int a  = blockIdx.y;
  if (j >= NDET) return;                // kills exactly wave 3 of block 18 (j 300..303)

  float th = (float)a * (float)(3.14159265358979323846 / 299.0);
  float c = cosf(th), s = sinf(th);
  float xj = fmaf((float)j, (float)(2.0 / 299.0), -1.0f);
  float pb = fmaf(c,  xj, 1.0f) * 149.5f - 149.5f * s;
  float qb = fmaf(-s, xj, 1.0f) * 149.5f - 149.5f * c;
  const float L = 76.5f, H = 222.5f;
  float lo = 0.f, hi = 299.0f;
  if (s > 1e-6f) {
    float inv = 1.0f / s;
    lo = fmaxf(lo, (L - pb) * inv); hi = fminf(hi, (H - pb) * inv);
  } else if (pb < L || pb > H) { hi = -1.f; }
  if (fabsf(c) > 1e-6f) {
    float inv = 1.0f / c;
    float t0 = (L - qb) * inv, t1 = (H - qb) * inv;
    lo = fmaxf(lo, fminf(t0, t1)); hi = fminf(hi, fmaxf(t0, t1));
  } else if (qb < L || qb > H) { hi = -1.f; }

  // wave-uniform union bounds over the 4 j's in this wave (empty chords give
  // lo=0, hi=-1 and contribute nothing; all-empty wave skips the loop)
  float lo_w = fminf(lo, __shfl_xor(lo, 16));
  lo_w = fminf(lo_w, __shfl_xor(lo_w, 32));
  float hi_w = fmaxf(hi, __shfl_xor(hi, 16));
  hi_w = fmaxf(hi_w, __shfl_xor(hi_w, 32));
  int i0w  = __builtin_amdgcn_readfirstlane((int)floorf(fmaxf(lo_w, 0.f)));
  int ihiw = __builtin_amdgcn_readfirstlane((int)floorf(hi_w));

  uint4* entW = &sLds[jrow * 17 + b];
  const uint4* entR = &sLds[jrow * 17];

  const char* Pc = (const char*)P;
  const char* Pcb = Pc + b * 16;
  const int PIXBASE = -76 * 149 * 256;             // (y*148+x) -> box offset bias

  float sE0 = 0.f, sE1 = 0.f, sA0 = 0.f, sA1 = 0.f;
  float fib = (float)i0w + (float)b;

  for (int ib = i0w; ib <= ihiw; ib += 16, fib += 16.f) {
    // Phase A: this lane computes sample (j, ib + b)
    {
      float px = fmaf(fib, s, pb);
      float py = fmaf(fib, c, qb);
      px = fminf(fmaxf(px, 76.5f), 222.0f);        // exact-zero clamp (see header)
      py = fminf(fmaxf(py, 76.5f), 222.0f);
      float x0f = floorf(px), y0f = floorf(py);
      float wx = px - x0f, wy = py - y0f;
      int idx = (int)fmaf(y0f, (float)WB, x0f);
      int off = (idx << 8) + PIXBASE;              // pixel stride 256 B
      float omx = 1.0f - wx, omy = 1.0f - wy;
      unsigned w0 = pk16u(omy * omx, omy * wx);
      unsigned w1 = pk16u(wy * omx,  wy * wx);
      *entW = make_uint4((unsigned)off, w0, w1, w1);
    }
    __builtin_amdgcn_wave_barrier();
    // Phase B: consume 16 entries, 2 groups of 8 (8 loads in flight)
#pragma unroll
    for (int g = 0; g < 2; ++g) {
      uint4 e[8];
#pragma unroll
      for (int u = 0; u < 8; ++u) e[u] = entR[g * 8 + u];
      uint4 q[8];
#pragma unroll
      for (int u = 0; u < 8; ++u)
        q[u] = *(const uint4*)(Pcb + (int)e[u].x);
#pragma unroll
      for (int u = 0; u < 8; ++u) {
        sE0 = fdot2(q[u].x, e[u].y, sE0);
        sE1 = fdot2(q[u].y, e[u].z, sE1);
        sA0 = fdot2(q[u].z, e[u].y, sA0);
        sA1 = fdot2(q[u].w, e[u].z, sA1);
      }
    }
    __builtin_amdgcn_wave_barrier();
  }
  float sumE = sE0 + sE1, sumA = sA0 + sA1;
  S[(a * NB + b) * NDET + j] = sumE * expf(-2.0f * sumA);  // VOXEL_MM = 2; layout [a][b][j]
}

// K3: per-angle 5-tap detector blur (reflect) + scale. S is [a][b][j] -> fully
// coalesced reads along j; out [b][a][j] coalesced writes.
__global__ void k_dblur(const float* __restrict__ S, const float* __restrict__ scale,
                        float* __restrict__ out) {
  int j = threadIdx.x;
  int a = blockIdx.x;
  int b = blockIdx.y;
  if (j >= NDET) return;
  float th = (float)a * (float)(3.14159265358979323846 / 299.0);
  float c = cosf(th), s = sinf(th);
  float u = fabsf(c) + fabsf(s);          // bw = 2u
  float u2 = u * u;
  float e1 = exp2f(-2.0f * u2);
  float e2 = exp2f(-8.0f * u2);
  float norm = 1.0f / (1.0f + 2.0f * (e1 + e2));
  float w2c = norm, w1c = e1 * norm, w0c = e2 * norm;
  const float* row = S + (a * NB + b) * NDET;
  float acc = 0.f;
#pragma unroll
  for (int tt = -2; tt <= 2; ++tt) {
    int jr = j + tt;
    if (jr < 0) jr = -jr;
    if (jr > 299) jr = 598 - jr;
    float w = (tt == 0) ? w2c : ((tt == 1 || tt == -1) ? w1c : w0c);
    acc = fmaf(w, row[jr], acc);
  }
  out[(b * NANG + a) * NDET + j] = acc * scale[b];
}

extern "C" void kernel_launch(void* const* d_in, const int* in_sizes, int n_in,
                              void* d_out, int out_size, void* d_ws, size_t ws_size,
                              hipStream_t stream) {
  const float* img   = (const float*)d_in[0];
  const float* att   = (const float*)d_in[1];
  const float* scale = (const float*)d_in[2];
  float* out = (float*)d_out;
  float* ws  = (float*)d_ws;

  // ws layout (floats): Q 148*148*16 uint4 (5.61 MB) | S 300*300*16 (5.76 MB)
  uint4*  Q  = (uint4*)ws;
  float*  S  = ws + 1401856;

  k_prep <<<dim3(10, 10, NB), 256, 0, stream>>>(img, att, Q);
  k_radon<<<dim3(19, NANG),   256, 0, stream>>>(Q, S);
  k_dblur<<<dim3(NANG, NB),   320, 0, stream>>>(S, scale, out);
}